// Round 10
// baseline (394.844 us; speedup 1.0000x reference)
//
#include <hip/hip_runtime.h>
#include <hip/hip_bf16.h>

// B=4, S=2048, D=1024, DH=64. Inputs/outputs are FLOAT32 (per reference).
typedef short bf16x8 __attribute__((ext_vector_type(8)));
typedef float f32x4  __attribute__((ext_vector_type(4)));
typedef _Float16 f16x8 __attribute__((ext_vector_type(8)));

#define MFMA16(a,b,c)  __builtin_amdgcn_mfma_f32_16x16x32_bf16((a),(b),(c),0,0,0)
#define MFMAF16(a,b,c) __builtin_amdgcn_mfma_f32_16x16x32_f16((a),(b),(c),0,0,0)

// async global->LDS: 16B per lane, lane i lands at lds_base + i*16
#define GLDS16(g,l) __builtin_amdgcn_global_load_lds( \
    (const __attribute__((address_space(1))) void*)(g), \
    (__attribute__((address_space(3))) void*)(l), 16, 0, 0)

__device__ __forceinline__ short f2bf(float f){
  union { float f; unsigned u; } v; v.f = f;
  unsigned r = v.u + 0x7fffu + ((v.u >> 16) & 1u);
  return (short)(r >> 16);
}
__device__ __forceinline__ float bf2f(short h){
  union { unsigned u; float f; } v; v.u = ((unsigned)(unsigned short)h) << 16;
  return v.f;
}
__device__ __forceinline__ void split8v(f32x4 a, f32x4 b, bf16x8& h, bf16x8& l){
  float t[8] = {a[0],a[1],a[2],a[3],b[0],b[1],b[2],b[3]};
  #pragma unroll
  for (int e = 0; e < 8; ++e){
    short hs = f2bf(t[e]);
    h[e] = hs;
    l[e] = f2bf(t[e] - bf2f(hs));
  }
}

// ---------------- P0 (fused): weight transpose+split (blocks 0..1535) + x split (1536..5631) ----------------
__global__ void k_prep(const float* w0, const float* w1, const float* w2,
                       const float* w3, const float* w4, const float* w5,
                       const float* __restrict__ x,
                       unsigned short* __restrict__ wth, unsigned short* __restrict__ wtl,
                       unsigned short* __restrict__ xh, unsigned short* __restrict__ xl){
  int gb = blockIdx.x;
  if (gb < 1536){
    int p = gb >> 8;
    const float* wp = p==0?w0:p==1?w1:p==2?w2:p==3?w3:p==4?w4:w5;
    int idx = (gb & 255)*256 + threadIdx.x;   // [0,65536)
    int n = idx >> 10, k = idx & 1023;
    float v = wp[k*64 + n];
    short hs = f2bf(v);
    wth[(size_t)p*65536 + n*1024 + k] = (unsigned short)hs;
    wtl[(size_t)p*65536 + n*1024 + k] = (unsigned short)f2bf(v - bf2f(hs));
  } else {
    size_t i = ((size_t)(gb - 1536)*256 + threadIdx.x)*8;
    f32x4 a = *(const f32x4*)(x + i);
    f32x4 b = *(const f32x4*)(x + i + 4);
    bf16x8 h, l;
    split8v(a, b, h, l);
    *(bf16x8*)(xh + i) = h;
    *(bf16x8*)(xl + i) = l;
  }
}

// ---------------- P1: projections + fused V-transpose epilogue ----------------
// bf16 h/l out for p 0..4; pg==1 blocks also emit Vu^T fp16 h/l; pg==2 blocks emit Vc^T fp16.
__global__ __launch_bounds__(256) void k_proj(
    const unsigned short* __restrict__ xh, const unsigned short* __restrict__ xl,
    const unsigned short* __restrict__ wth, const unsigned short* __restrict__ wtl,
    unsigned short* __restrict__ projh, unsigned short* __restrict__ projl,
    _Float16* __restrict__ vct, _Float16* __restrict__ vuth, _Float16* __restrict__ vutl){
  __shared__ __align__(16) char sm[49152];  // xh 8K | xl 8K | w0h 8K | w0l 8K | w1h 8K | w1l 8K
  int blk = blockIdx.x;
  int rb = blk/3, pg = blk - rb*3;
  int tid = threadIdx.x, w = tid >> 6, lane = tid & 63;
  int lm = lane & 15, quad = lane >> 4;
  int srow = lane >> 3, scg = (lane & 7) ^ srow;
  const char* xhg = (const char*)xh;
  const char* xlg = (const char*)xl;
  const char* w0h = (const char*)wth + (size_t)(pg*2  )*131072;
  const char* w0l = (const char*)wtl + (size_t)(pg*2  )*131072;
  const char* w1h = (const char*)wth + (size_t)(pg*2+1)*131072;
  const char* w1l = (const char*)wtl + (size_t)(pg*2+1)*131072;
  f32x4 acc[2][4] = {};
  for (int k0 = 0; k0 < 1024; k0 += 64){
    __syncthreads();
    size_t cb = (size_t)k0*2 + scg*16;
    #pragma unroll
    for (int i2 = 0; i2 < 2; ++i2){
      int i = w*2 + i2;
      size_t gx = (size_t)(rb*64 + i*8 + srow)*2048 + cb;
      size_t gw = (size_t)(i*8 + srow)*2048 + cb;
      GLDS16(xhg + gx, sm +         i*1024);
      GLDS16(xlg + gx, sm +  8192 + i*1024);
      GLDS16(w0h + gw, sm + 16384 + i*1024);
      GLDS16(w0l + gw, sm + 24576 + i*1024);
      GLDS16(w1h + gw, sm + 32768 + i*1024);
      GLDS16(w1l + gw, sm + 40960 + i*1024);
    }
    __syncthreads();
    #pragma unroll
    for (int ks = 0; ks < 2; ++ks){
      int ra = w*16 + lm;
      int offa = ra*128 + (((ks*4+quad) ^ (ra&7))*16);
      bf16x8 ah = *(const bf16x8*)(sm + offa);
      bf16x8 al = *(const bf16x8*)(sm + 8192 + offa);
      #pragma unroll
      for (int sub = 0; sub < 2; ++sub){
        #pragma unroll
        for (int n = 0; n < 4; ++n){
          int r = n*16 + lm;
          int off = r*128 + (((ks*4+quad) ^ (r&7))*16);
          bf16x8 bh = *(const bf16x8*)(sm + 16384 + sub*16384 + off);
          bf16x8 bl = *(const bf16x8*)(sm + 24576 + sub*16384 + off);
          acc[sub][n] = MFMA16(ah, bh, acc[sub][n]);
          acc[sub][n] = MFMA16(ah, bl, acc[sub][n]);
          acc[sub][n] = MFMA16(al, bh, acc[sub][n]);
        }
      }
    }
  }
  #pragma unroll
  for (int sub = 0; sub < 2; ++sub){
    int p = pg*2 + sub;
    if (p != 5){
      unsigned short* oph = projh + (size_t)p*524288;
      unsigned short* opl = projl + (size_t)p*524288;
      #pragma unroll
      for (int n = 0; n < 4; ++n)
        #pragma unroll
        for (int e = 0; e < 4; ++e){
          int r = rb*64 + w*16 + quad*4 + e;
          float f = acc[sub][n][e];
          short hs = f2bf(f);
          oph[(size_t)r*64 + n*16 + lm] = (unsigned short)hs;
          opl[(size_t)r*64 + n*16 + lm] = (unsigned short)f2bf(f - bf2f(hs));
        }
    }
  }
  // fused transpose: pg==1 -> Vu (sub 0) to vuth/vutl; pg==2 -> Vc (sub 1) to vct
  if (pg == 1 || pg == 2){
    int sub = (pg == 1) ? 0 : 1;
    float (*T)[65] = (float (*)[65])sm;
    __syncthreads();                          // main-loop LDS reads done
    #pragma unroll
    for (int n = 0; n < 4; ++n)
      #pragma unroll
      for (int e = 0; e < 4; ++e)
        T[w*16 + quad*4 + e][n*16 + lm] = acc[sub][n][e];
    __syncthreads();
    int b2 = rb >> 5, sl = (rb & 31)*64;
    int d = tid >> 2, sp = (tid & 3)*16;
    size_t o = (size_t)b2*131072 + (size_t)d*2048 + sl + sp;
    if (sub == 1){
      f16x8 h0, h1;
      #pragma unroll
      for (int j = 0; j < 8; ++j) h0[j] = (_Float16)T[sp + j][d];
      #pragma unroll
      for (int j = 0; j < 8; ++j) h1[j] = (_Float16)T[sp + 8 + j][d];
      *(f16x8*)(vct + o) = h0; *(f16x8*)(vct + o + 8) = h1;
    } else {
      f16x8 h0, h1, l0, l1;
      #pragma unroll
      for (int j = 0; j < 8; ++j){
        float f = T[sp + j][d];
        _Float16 h = (_Float16)f;
        h0[j] = h; l0[j] = (_Float16)(f - (float)h);
      }
      #pragma unroll
      for (int j = 0; j < 8; ++j){
        float f = T[sp + 8 + j][d];
        _Float16 h = (_Float16)f;
        h1[j] = h; l1[j] = (_Float16)(f - (float)h);
      }
      *(f16x8*)(vuth + o) = h0; *(f16x8*)(vuth + o + 8) = h1;
      *(f16x8*)(vutl + o) = l0; *(f16x8*)(vutl + o + 8) = l1;
    }
  }
}

// ---------------- P2: sig tiles (136) + diag t1 tiles (16), FUSED W-GEMM, direct loads ----------------
__global__ __launch_bounds__(256,3) void k_p2(
    const unsigned short* __restrict__ ph, const unsigned short* __restrict__ pl,
    const _Float16* __restrict__ vuth, const _Float16* __restrict__ vutl,
    _Float16* __restrict__ sg, _Float16* __restrict__ t1d, float* __restrict__ W){
  __shared__ __align__(16) char sm[32768];   // 128x128 f16 tile (XOR-swizzled)
  int b = blockIdx.y;
  int t = blockIdx.x;                        // [0,152): 136 sig + 16 diag-t1
  bool isSig = t < 136;
  int a = 0, bb = 0;
  if (isSig){
    #pragma unroll 1
    for (int aa = 0; aa < 16; ++aa){
      int c = 16 - aa;
      if (t < c){ a = aa; bb = aa + t; break; }
      t -= c;
    }
  } else {
    a = bb = t - 136;
  }
  int pa = isSig ? 0 : 3;                    // A = Qu : Qc
  int pb = isSig ? 1 : 2;                    // B = Ku : Vu
  const char* Ahg = (const char*)ph + (size_t)pa*1048576;
  const char* Alg = (const char*)pl + (size_t)pa*1048576;
  const char* Bhg = (const char*)ph + (size_t)pb*1048576;
  const char* Blg = (const char*)pl + (size_t)pb*1048576;
  int tid = threadIdx.x, w = tid >> 6, lane = tid & 63;
  int lm = lane & 15, quad = lane >> 4;
  int wm = (w & 1)*64, wn = (w >> 1)*64;
  f32x4 acc[4][4] = {};
  #pragma unroll
  for (int ks = 0; ks < 2; ++ks){
    bf16x8 bh[4], bl[4];
    #pragma unroll
    for (int n = 0; n < 4; ++n){
      size_t off = (size_t)(b*2048 + bb*128 + wn + n*16 + lm)*128 + (ks*32 + quad*8)*2;
      bh[n] = *(const bf16x8*)(Bhg + off);
      bl[n] = *(const bf16x8*)(Blg + off);
    }
    #pragma unroll
    for (int m = 0; m < 4; ++m){
      size_t off = (size_t)(b*2048 + a*128 + wm + m*16 + lm)*128 + (ks*32 + quad*8)*2;
      bf16x8 ah = *(const bf16x8*)(Ahg + off);
      bf16x8 al = *(const bf16x8*)(Alg + off);
      #pragma unroll
      for (int n = 0; n < 4; ++n){
        acc[m][n] = MFMA16(ah, bh[n], acc[m][n]);
        acc[m][n] = MFMA16(ah, bl[n], acc[m][n]);
        acc[m][n] = MFMA16(al, bh[n], acc[m][n]);
      }
    }
  }
  // swizzled 128x128 f16 tile: byte ^= (row&7)<<4
  #pragma unroll
  for (int m = 0; m < 4; ++m){
    #pragma unroll
    for (int n = 0; n < 4; ++n){
      #pragma unroll
      for (int e = 0; e < 4; ++e){
        int il = wm + m*16 + quad*4 + e;
        int jl = wn + n*16 + lm;
        int gi = a*128 + il, gj = bb*128 + jl;
        float v = acc[m][n][e];
        float outv;
        if (isSig) outv = (gj >  gi) ? (1.0f/(1.0f + __expf(-v*0.125f))) : 0.0f;
        else       outv = (gj <= gi) ? v : 0.0f;   // raw (unscaled) diag t1
        *(_Float16*)(sm + ((il*256 + jl*2) ^ ((il & 7) << 4))) = (_Float16)outv;
      }
    }
  }
  __syncthreads();
  char* outp = isSig
    ? (char*)(sg + (size_t)b*4194304 + (size_t)(a*128)*2048 + bb*128)
    : (char*)t1d + (size_t)(b*16 + a)*32768;
  size_t rstride = isSig ? 4096 : 256;       // bytes per row in dest
  #pragma unroll
  for (int r = 0; r < 8; ++r){
    int lrow = w*32 + r*4 + (lane >> 4);
    int c16 = lane & 15;
    f32x4 vv = *(const f32x4*)(sm + ((lrow*256 + c16*16) ^ ((lrow & 7) << 4)));
    *(f32x4*)(outp + (size_t)lrow*rstride + c16*16) = vv;
  }
  // fused W-GEMM: W[(c=bb,ck=a)] = sig_tile (LDS) @ Vu^T[bb], 128k x 64d, K=128 fp16 h/l
  if (isSig){
    int wm2 = (w & 1)*64, wn2 = (w >> 1)*32;
    f32x4 acc2[4][2] = {};
    #pragma unroll
    for (int ks = 0; ks < 4; ++ks){
      f16x8 bh2[2], bl2[2];
      #pragma unroll
      for (int n = 0; n < 2; ++n){
        int d = wn2 + n*16 + lm;
        size_t jo = ((size_t)(b*64 + d)*2048 + bb*128 + ks*32 + quad*8)*2;
        bh2[n] = *(const f16x8*)((const char*)vuth + jo);
        bl2[n] = *(const f16x8*)((const char*)vutl + jo);
      }
      #pragma unroll
      for (int m = 0; m < 4; ++m){
        int k = wm2 + m*16 + lm;
        f16x8 af = *(const f16x8*)(sm + ((k*256 + ks*64 + quad*16) ^ ((k & 7) << 4)));
        #pragma unroll
        for (int n = 0; n < 2; ++n){
          acc2[m][n] = MFMAF16(af, bh2[n], acc2[m][n]);
          acc2[m][n] = MFMAF16(af, bl2[n], acc2[m][n]);
        }
      }
    }
    float* Wp = W + (size_t)(b*136 + bb*(bb+1)/2 + a)*8192;
    #pragma unroll
    for (int m = 0; m < 4; ++m)
      #pragma unroll
      for (int n = 0; n < 2; ++n)
        #pragma unroll
        for (int e = 0; e < 4; ++e){
          int r = wm2 + m*16 + quad*4 + e;
          int col = wn2 + n*16 + lm;
          Wp[r*64 + col] = acc2[m][n][e];
        }
  }
}

// ---------------- P2b: parallel prefix P[ci][ck] = sum_{c in [ck,ci)} W[c][ck] -> bf16 h/l ----------------
__global__ __launch_bounds__(256) void k_scan(const float* __restrict__ W,
    unsigned short* __restrict__ Ph, unsigned short* __restrict__ Pl){
  int g = blockIdx.x, b = blockIdx.y;
  int ck = g >> 2, ksub = g & 3;
  if (ck >= 15) return;                      // ck=15 feeds nothing
  int tid = threadIdx.x;
  int rl = ksub*32 + (tid >> 3);             // row within 128-row chunk
  int col = (tid & 7)*8;
  float acc[8] = {};
  #pragma unroll 1
  for (int c = ck; c < 15; ++c){
    const float* wt = W + (size_t)(b*136 + c*(c+1)/2 + ck)*8192 + rl*64 + col;
    f32x4 v0 = *(const f32x4*)wt;
    f32x4 v1 = *(const f32x4*)(wt + 4);
    #pragma unroll
    for (int e = 0; e < 4; ++e){ acc[e] += v0[e]; acc[4+e] += v1[e]; }
    size_t o = ((size_t)(b*16 + c + 1)*2048 + ck*128 + rl)*64 + col;
    bf16x8 h, l;
    #pragma unroll
    for (int e = 0; e < 8; ++e){
      short hs = f2bf(acc[e]);
      h[e] = hs;
      l[e] = f2bf(acc[e] - bf2f(hs));
    }
    *(bf16x8*)(Ph + o) = h;
    *(bf16x8*)(Pl + o) = l;
  }
}

// ---------------- P3+P4 FUSED (flash-style): per 128-row chunk ci, loop ck=0..ci ----------------
// Online softmax: running m (reg of thread tid<128), l likewise; O acc in PV-wave registers.
// Per ck tile: logits (verbatim R9 k_p3 compute) -> row-max (shfl+LDS) -> m/F update ->
// rescale O, P=exp, PV MFMA (k_p2's swizzled af pattern + k_p4's V-frag pattern), l update.
// Kills the 33.5MB lg write + 17MB read + one launch + one exp sweep. Bytes ~65MB vs ~115MB.
// Grid (16,B): byte-bound kernel family (R8: occupancy-invariant), so 64 blocks is acceptable.
__global__ __launch_bounds__(256,1) void k_fuse(
    const unsigned short* __restrict__ ph, const unsigned short* __restrict__ pl,
    const _Float16* __restrict__ t1d, const _Float16* __restrict__ sg,
    const unsigned short* __restrict__ Ph, const unsigned short* __restrict__ Pl,
    const _Float16* __restrict__ vct, float* __restrict__ out){
  __shared__ __align__(16) char sm[32768];   // 128x128 f16 logits tile (XOR-swizzled)
  __shared__ float Mld[128], M2s[2][128], Fz[128], S2[128];
  int ci = blockIdx.x, b = blockIdx.y;
  int tid = threadIdx.x, w = tid >> 6, lane = tid & 63;
  int lm = lane & 15, quad = lane >> 4;
  int wm = (w & 1)*64, wn = (w >> 1)*64;

  const char* Qh = (const char*)ph + (size_t)3*1048576;
  const char* Ql = (const char*)pl + (size_t)3*1048576;
  const char* Kh = (const char*)ph + (size_t)4*1048576;
  const char* Kl = (const char*)pl + (size_t)4*1048576;
  const char* t1b = (const char*)t1d + (size_t)(b*16 + ci)*32768;
  const char* sgb = (const char*)sg + (size_t)b*8388608;
  const _Float16* vb = vct + (size_t)b*131072;

  float m_r = -3.0e38f, l_r = 0.0f;          // row state, owned by thread tid<128 (row=tid)
  f32x4 Ov[2][4] = {};                       // PV acc: row w*32+m2*16+quad*4+e, col n*16+lm

  for (int ck = 0; ck <= ci; ++ck){
    // ---- logits tile (R9 k_p3 compute, verbatim) ----
    f32x4 su[4][4] = {}, sc[4][4] = {};
    bool hasP = (ck < ci);
    #pragma unroll
    for (int ks = 0; ks < 2; ++ks){
      bf16x8 kh[4], kl[4], bh[4], bl[4];
      #pragma unroll
      for (int n = 0; n < 4; ++n){
        size_t offk = (size_t)(b*2048 + ck*128 + wn + n*16 + lm)*128 + (ks*32 + quad*8)*2;
        kh[n] = *(const bf16x8*)(Kh + offk);
        kl[n] = *(const bf16x8*)(Kl + offk);
      }
      if (hasP){
        #pragma unroll
        for (int n = 0; n < 4; ++n){
          size_t offp = (((size_t)(b*16 + ci)*2048 + ck*128 + wn + n*16 + lm)*64 + ks*32 + quad*8)*2;
          bh[n] = *(const bf16x8*)((const char*)Ph + offp);
          bl[n] = *(const bf16x8*)((const char*)Pl + offp);
        }
      }
      #pragma unroll
      for (int m = 0; m < 4; ++m){
        size_t offq = (size_t)(b*2048 + ci*128 + wm + m*16 + lm)*128 + (ks*32 + quad*8)*2;
        bf16x8 ah = *(const bf16x8*)(Qh + offq);
        bf16x8 al = *(const bf16x8*)(Ql + offq);
        #pragma unroll
        for (int n = 0; n < 4; ++n){
          sc[m][n] = MFMA16(ah, kh[n], sc[m][n]);
          sc[m][n] = MFMA16(ah, kl[n], sc[m][n]);
          sc[m][n] = MFMA16(al, kh[n], sc[m][n]);
        }
        if (hasP){
          #pragma unroll
          for (int n = 0; n < 4; ++n){
            su[m][n] = MFMA16(ah, bh[n], su[m][n]);
            su[m][n] = MFMA16(ah, bl[n], su[m][n]);
            su[m][n] = MFMA16(al, bh[n], su[m][n]);
          }
        }
      }
    }
    #pragma unroll
    for (int ks = 0; ks < 4; ++ks){
      f16x8 bs[4];
      #pragma unroll
      for (int n = 0; n < 4; ++n)
        bs[n] = *(const f16x8*)(sgb + ((size_t)(ck*128 + wn + n*16 + lm)*2048 + ci*128 + ks*32 + quad*8)*2);
      #pragma unroll
      for (int m = 0; m < 4; ++m){
        f16x8 at = *(const f16x8*)(t1b + ((wm + m*16 + lm)*128 + ks*32 + quad*8)*2);
        #pragma unroll
        for (int n = 0; n < 4; ++n)
          su[m][n] = MFMAF16(at, bs[n], su[m][n]);
      }
    }
    // ---- epilogue: logits -> LDS (masked, swizzled) + per-row half-max ----
    bool diag = (ck == ci);
    #pragma unroll
    for (int m = 0; m < 4; ++m){
      f32x4 hm = { -3.0e38f, -3.0e38f, -3.0e38f, -3.0e38f };
      #pragma unroll
      for (int n = 0; n < 4; ++n){
        #pragma unroll
        for (int e = 0; e < 4; ++e){
          int il = wm + m*16 + quad*4 + e;
          int jl = wn + n*16 + lm;
          float xv = 0.125f*su[m][n][e];
          float sg1 = 1.0f/(1.0f + __expf(-xv));
          float val = sc[m][n][e]*0.125f - xv*sg1;
          bool keep = !diag || (jl <= il);
          *(_Float16*)(sm + ((il*256 + jl*2) ^ ((il & 7) << 4))) =
              keep ? (_Float16)val : (_Float16)(-65504.0f);
          if (keep) hm[e] = fmaxf(hm[e], val);
        }
      }
      #pragma unroll
      for (int e = 0; e < 4; ++e){
        float v = hm[e];
        v = fmaxf(v, __shfl_xor(v, 1));
        v = fmaxf(v, __shfl_xor(v, 2));
        v = fmaxf(v, __shfl_xor(v, 4));
        v = fmaxf(v, __shfl_xor(v, 8));
        if (lm == 0) M2s[wn >> 6][wm + m*16 + quad*4 + e] = v;
      }
    }
    __syncthreads();                          // logits + M2s visible
    if (tid < 128){
      float mnew = fmaxf(m_r, fmaxf(M2s[0][tid], M2s[1][tid]));
      Fz[tid] = __expf(m_r - mnew);
      m_r = mnew;
      Mld[tid] = mnew;
    }
    __syncthreads();                          // Fz/Mld visible
    // ---- PV: rescale O, P=exp(L-m), MFMA accumulate, row-sum ----
    #pragma unroll
    for (int m2 = 0; m2 < 2; ++m2)
      #pragma unroll
      for (int e = 0; e < 4; ++e){
        float f = Fz[w*32 + m2*16 + quad*4 + e];
        #pragma unroll
        for (int n = 0; n < 4; ++n) Ov[m2][n][e] *= f;
      }
    float mr0 = Mld[w*32 + lm], mr1 = Mld[w*32 + 16 + lm];
    float s0 = 0.0f, s1 = 0.0f;
    #pragma unroll
    for (int ks = 0; ks < 4; ++ks){
      f16x8 bv[4];
      #pragma unroll
      for (int n = 0; n < 4; ++n)
        bv[n] = *(const f16x8*)(vb + (size_t)(n*16 + lm)*2048 + ck*128 + ks*32 + quad*8);
      #pragma unroll
      for (int m2 = 0; m2 < 2; ++m2){
        int r = w*32 + m2*16 + lm;
        f16x8 Lv = *(const f16x8*)(sm + ((r*256 + ks*64 + quad*16) ^ ((r & 7) << 4)));
        float mrr = m2 ? mr1 : mr0;
        f16x8 af;
        #pragma unroll
        for (int e = 0; e < 8; ++e){
          float p = __expf((float)Lv[e] - mrr);
          if (m2) s1 += p; else s0 += p;
          af[e] = (_Float16)p;
        }
        #pragma unroll
        for (int n = 0; n < 4; ++n)
          Ov[m2][n] = MFMAF16(af, bv[n], Ov[m2][n]);
      }
    }
    s0 += __shfl_xor(s0, 16); s0 += __shfl_xor(s0, 32);
    s1 += __shfl_xor(s1, 16); s1 += __shfl_xor(s1, 32);
    if (quad == 0){ S2[w*32 + lm] = s0; S2[w*32 + 16 + lm] = s1; }
    __syncthreads();                          // S2 visible; PV reads of sm done
    if (tid < 128) l_r = l_r * Fz[tid] + S2[tid];
  }
  // ---- final: divide by l and store ----
  if (tid < 128) S2[tid] = l_r;
  __syncthreads();
  #pragma unroll
  for (int m2 = 0; m2 < 2; ++m2)
    #pragma unroll
    for (int e = 0; e < 4; ++e){
      int r = w*32 + m2*16 + quad*4 + e;
      float z = S2[r];
      #pragma unroll
      for (int n = 0; n < 4; ++n)
        out[((size_t)b*2048 + ci*128 + r)*64 + n*16 + lm] = Ov[m2][n][e] / z;
    }
}

// ---------------- workspace layout (bytes) ----------------
static const size_t OFF_WTH   = 4194304;     // 6 x 64x1024 bf16
static const size_t OFF_WTL   = 4980736;
static const size_t OFF_PROJH = 5767168;     // 6 x 8192x64 bf16
static const size_t OFF_PROJL = 12058624;
static const size_t OFF_VCT   = 18350080;    // 4 x 64x2048 f16
static const size_t OFF_SG    = 19398656;    // 4 x 2048^2 f16
static const size_t OFF_T1D   = 86507520;    // 4 x 16 x 128x128 f16
static const size_t OFF_PH    = 88604672;    // 4 x 16 x 2048x64 bf16
static const size_t OFF_PL    = 105381888;
static const size_t OFF_VUTH  = 122159104;   // 4 x 64x2048 f16
static const size_t OFF_VUTL  = 123207680;
static const size_t OFF_XH    = 124256256;   // 8192x1024 bf16
static const size_t OFF_XL    = 141033472;
// W (4 x 136 x 128x64 f32 = 17,825,792 B) reuses the xh/xl region: k_proj is the
// last consumer of xh/xl; k_p2 (the W producer) launches strictly after it in-stream.
static const size_t OFF_W     = OFF_XH;
// total = 157,810,688 bytes

extern "C" void kernel_launch(void* const* d_in, const int* in_sizes, int n_in,
                              void* d_out, int out_size, void* d_ws, size_t ws_size,
                              hipStream_t stream){
  (void)in_sizes; (void)n_in; (void)out_size; (void)ws_size;
  const float* x = (const float*)d_in[0];
  char* ws = (char*)d_ws;
  unsigned short* wth   = (unsigned short*)(ws + OFF_WTH);
  unsigned short* wtl   = (unsigned short*)(ws + OFF_WTL);
  unsigned short* projh = (unsigned short*)(ws + OFF_PROJH);
  unsigned short* projl = (unsigned short*)(ws + OFF_PROJL);
  _Float16*       vct   = (_Float16*)(ws + OFF_VCT);
  _Float16*       sg    = (_Float16*)(ws + OFF_SG);
  _Float16*       t1d   = (_Float16*)(ws + OFF_T1D);
  unsigned short* Phb   = (unsigned short*)(ws + OFF_PH);
  unsigned short* Plb   = (unsigned short*)(ws + OFF_PL);
  _Float16*       vuth  = (_Float16*)(ws + OFF_VUTH);
  _Float16*       vutl  = (_Float16*)(ws + OFF_VUTL);
  unsigned short* xh    = (unsigned short*)(ws + OFF_XH);
  unsigned short* xl    = (unsigned short*)(ws + OFF_XL);
  float*          Wb    = (float*)(ws + OFF_W);

  k_prep  <<<dim3(5632),   256, 0, stream>>>((const float*)d_in[1], (const float*)d_in[2],
                                             (const float*)d_in[3], (const float*)d_in[4],
                                             (const float*)d_in[5], (const float*)d_in[6],
                                             x, wth, wtl, xh, xl);
  k_proj  <<<dim3(384),    256, 0, stream>>>(xh, xl, wth, wtl, projh, projl, vct, vuth, vutl);
  k_p2    <<<dim3(152,4),  256, 0, stream>>>(projh, projl, vuth, vutl, sg, t1d, Wb);
  k_scan  <<<dim3(64,4),   256, 0, stream>>>(Wb, Phb, Plb);
  k_fuse  <<<dim3(16,4),   256, 0, stream>>>(projh, projl, t1d, sg, Phb, Plb, vct, (float*)d_out);
}

// Round 12
// 225.785 us; speedup vs baseline: 1.7488x; 1.7488x over previous
//
#include <hip/hip_runtime.h>
#include <hip/hip_bf16.h>

// B=4, S=2048, D=1024, DH=64. Inputs/outputs are FLOAT32 (per reference).
typedef short bf16x8 __attribute__((ext_vector_type(8)));
typedef float f32x4  __attribute__((ext_vector_type(4)));
typedef _Float16 f16x8 __attribute__((ext_vector_type(8)));

#define MFMA16(a,b,c)  __builtin_amdgcn_mfma_f32_16x16x32_bf16((a),(b),(c),0,0,0)
#define MFMAF16(a,b,c) __builtin_amdgcn_mfma_f32_16x16x32_f16((a),(b),(c),0,0,0)

// async global->LDS: 16B per lane, lane i lands at lds_base + i*16
#define GLDS16(g,l) __builtin_amdgcn_global_load_lds( \
    (const __attribute__((address_space(1))) void*)(g), \
    (__attribute__((address_space(3))) void*)(l), 16, 0, 0)

__device__ __forceinline__ short f2bf(float f){
  union { float f; unsigned u; } v; v.f = f;
  unsigned r = v.u + 0x7fffu + ((v.u >> 16) & 1u);
  return (short)(r >> 16);
}
__device__ __forceinline__ float bf2f(short h){
  union { unsigned u; float f; } v; v.u = ((unsigned)(unsigned short)h) << 16;
  return v.f;
}
__device__ __forceinline__ void split8v(f32x4 a, f32x4 b, bf16x8& h, bf16x8& l){
  float t[8] = {a[0],a[1],a[2],a[3],b[0],b[1],b[2],b[3]};
  #pragma unroll
  for (int e = 0; e < 8; ++e){
    short hs = f2bf(t[e]);
    h[e] = hs;
    l[e] = f2bf(t[e] - bf2f(hs));
  }
}

// ---------------- P0 (fused): weight transpose+split (blocks 0..1535) + x split (1536..5631) ----------------
__global__ void k_prep(const float* w0, const float* w1, const float* w2,
                       const float* w3, const float* w4, const float* w5,
                       const float* __restrict__ x,
                       unsigned short* __restrict__ wth, unsigned short* __restrict__ wtl,
                       unsigned short* __restrict__ xh, unsigned short* __restrict__ xl){
  int gb = blockIdx.x;
  if (gb < 1536){
    int p = gb >> 8;
    const float* wp = p==0?w0:p==1?w1:p==2?w2:p==3?w3:p==4?w4:w5;
    int idx = (gb & 255)*256 + threadIdx.x;   // [0,65536)
    int n = idx >> 10, k = idx & 1023;
    float v = wp[k*64 + n];
    short hs = f2bf(v);
    wth[(size_t)p*65536 + n*1024 + k] = (unsigned short)hs;
    wtl[(size_t)p*65536 + n*1024 + k] = (unsigned short)f2bf(v - bf2f(hs));
  } else {
    size_t i = ((size_t)(gb - 1536)*256 + threadIdx.x)*8;
    f32x4 a = *(const f32x4*)(x + i);
    f32x4 b = *(const f32x4*)(x + i + 4);
    bf16x8 h, l;
    split8v(a, b, h, l);
    *(bf16x8*)(xh + i) = h;
    *(bf16x8*)(xl + i) = l;
  }
}

// ---------------- P1: projections + fused V-transpose epilogue ----------------
__global__ __launch_bounds__(256) void k_proj(
    const unsigned short* __restrict__ xh, const unsigned short* __restrict__ xl,
    const unsigned short* __restrict__ wth, const unsigned short* __restrict__ wtl,
    unsigned short* __restrict__ projh, unsigned short* __restrict__ projl,
    _Float16* __restrict__ vct, _Float16* __restrict__ vuth, _Float16* __restrict__ vutl){
  __shared__ __align__(16) char sm[49152];  // xh 8K | xl 8K | w0h 8K | w0l 8K | w1h 8K | w1l 8K
  int blk = blockIdx.x;
  int rb = blk/3, pg = blk - rb*3;
  int tid = threadIdx.x, w = tid >> 6, lane = tid & 63;
  int lm = lane & 15, quad = lane >> 4;
  int srow = lane >> 3, scg = (lane & 7) ^ srow;
  const char* xhg = (const char*)xh;
  const char* xlg = (const char*)xl;
  const char* w0h = (const char*)wth + (size_t)(pg*2  )*131072;
  const char* w0l = (const char*)wtl + (size_t)(pg*2  )*131072;
  const char* w1h = (const char*)wth + (size_t)(pg*2+1)*131072;
  const char* w1l = (const char*)wtl + (size_t)(pg*2+1)*131072;
  f32x4 acc[2][4] = {};
  for (int k0 = 0; k0 < 1024; k0 += 64){
    __syncthreads();
    size_t cb = (size_t)k0*2 + scg*16;
    #pragma unroll
    for (int i2 = 0; i2 < 2; ++i2){
      int i = w*2 + i2;
      size_t gx = (size_t)(rb*64 + i*8 + srow)*2048 + cb;
      size_t gw = (size_t)(i*8 + srow)*2048 + cb;
      GLDS16(xhg + gx, sm +         i*1024);
      GLDS16(xlg + gx, sm +  8192 + i*1024);
      GLDS16(w0h + gw, sm + 16384 + i*1024);
      GLDS16(w0l + gw, sm + 24576 + i*1024);
      GLDS16(w1h + gw, sm + 32768 + i*1024);
      GLDS16(w1l + gw, sm + 40960 + i*1024);
    }
    __syncthreads();
    #pragma unroll
    for (int ks = 0; ks < 2; ++ks){
      int ra = w*16 + lm;
      int offa = ra*128 + (((ks*4+quad) ^ (ra&7))*16);
      bf16x8 ah = *(const bf16x8*)(sm + offa);
      bf16x8 al = *(const bf16x8*)(sm + 8192 + offa);
      #pragma unroll
      for (int sub = 0; sub < 2; ++sub){
        #pragma unroll
        for (int n = 0; n < 4; ++n){
          int r = n*16 + lm;
          int off = r*128 + (((ks*4+quad) ^ (r&7))*16);
          bf16x8 bh = *(const bf16x8*)(sm + 16384 + sub*16384 + off);
          bf16x8 bl = *(const bf16x8*)(sm + 24576 + sub*16384 + off);
          acc[sub][n] = MFMA16(ah, bh, acc[sub][n]);
          acc[sub][n] = MFMA16(ah, bl, acc[sub][n]);
          acc[sub][n] = MFMA16(al, bh, acc[sub][n]);
        }
      }
    }
  }
  #pragma unroll
  for (int sub = 0; sub < 2; ++sub){
    int p = pg*2 + sub;
    if (p != 5){
      unsigned short* oph = projh + (size_t)p*524288;
      unsigned short* opl = projl + (size_t)p*524288;
      #pragma unroll
      for (int n = 0; n < 4; ++n)
        #pragma unroll
        for (int e = 0; e < 4; ++e){
          int r = rb*64 + w*16 + quad*4 + e;
          float f = acc[sub][n][e];
          short hs = f2bf(f);
          oph[(size_t)r*64 + n*16 + lm] = (unsigned short)hs;
          opl[(size_t)r*64 + n*16 + lm] = (unsigned short)f2bf(f - bf2f(hs));
        }
    }
  }
  // fused transpose: pg==1 -> Vu (sub 0) to vuth/vutl; pg==2 -> Vc (sub 1) to vct
  if (pg == 1 || pg == 2){
    int sub = (pg == 1) ? 0 : 1;
    float (*T)[65] = (float (*)[65])sm;
    __syncthreads();                          // main-loop LDS reads done
    #pragma unroll
    for (int n = 0; n < 4; ++n)
      #pragma unroll
      for (int e = 0; e < 4; ++e)
        T[w*16 + quad*4 + e][n*16 + lm] = acc[sub][n][e];
    __syncthreads();
    int b2 = rb >> 5, sl = (rb & 31)*64;
    int d = tid >> 2, sp = (tid & 3)*16;
    size_t o = (size_t)b2*131072 + (size_t)d*2048 + sl + sp;
    if (sub == 1){
      f16x8 h0, h1;
      #pragma unroll
      for (int j = 0; j < 8; ++j) h0[j] = (_Float16)T[sp + j][d];
      #pragma unroll
      for (int j = 0; j < 8; ++j) h1[j] = (_Float16)T[sp + 8 + j][d];
      *(f16x8*)(vct + o) = h0; *(f16x8*)(vct + o + 8) = h1;
    } else {
      f16x8 h0, h1, l0, l1;
      #pragma unroll
      for (int j = 0; j < 8; ++j){
        float f = T[sp + j][d];
        _Float16 h = (_Float16)f;
        h0[j] = h; l0[j] = (_Float16)(f - (float)h);
      }
      #pragma unroll
      for (int j = 0; j < 8; ++j){
        float f = T[sp + 8 + j][d];
        _Float16 h = (_Float16)f;
        h1[j] = h; l1[j] = (_Float16)(f - (float)h);
      }
      *(f16x8*)(vuth + o) = h0; *(f16x8*)(vuth + o + 8) = h1;
      *(f16x8*)(vutl + o) = l0; *(f16x8*)(vutl + o + 8) = l1;
    }
  }
}

// ---------------- P2: sig tiles (136) + diag t1 tiles (16), FUSED W-GEMM, direct loads ----------------
__global__ __launch_bounds__(256,3) void k_p2(
    const unsigned short* __restrict__ ph, const unsigned short* __restrict__ pl,
    const _Float16* __restrict__ vuth, const _Float16* __restrict__ vutl,
    _Float16* __restrict__ sg, _Float16* __restrict__ t1d, float* __restrict__ W){
  __shared__ __align__(16) char sm[32768];   // 128x128 f16 tile (XOR-swizzled)
  int b = blockIdx.y;
  int t = blockIdx.x;                        // [0,152): 136 sig + 16 diag-t1
  bool isSig = t < 136;
  int a = 0, bb = 0;
  if (isSig){
    #pragma unroll 1
    for (int aa = 0; aa < 16; ++aa){
      int c = 16 - aa;
      if (t < c){ a = aa; bb = aa + t; break; }
      t -= c;
    }
  } else {
    a = bb = t - 136;
  }
  int pa = isSig ? 0 : 3;                    // A = Qu : Qc
  int pb = isSig ? 1 : 2;                    // B = Ku : Vu
  const char* Ahg = (const char*)ph + (size_t)pa*1048576;
  const char* Alg = (const char*)pl + (size_t)pa*1048576;
  const char* Bhg = (const char*)ph + (size_t)pb*1048576;
  const char* Blg = (const char*)pl + (size_t)pb*1048576;
  int tid = threadIdx.x, w = tid >> 6, lane = tid & 63;
  int lm = lane & 15, quad = lane >> 4;
  int wm = (w & 1)*64, wn = (w >> 1)*64;
  f32x4 acc[4][4] = {};
  #pragma unroll
  for (int ks = 0; ks < 2; ++ks){
    bf16x8 bh[4], bl[4];
    #pragma unroll
    for (int n = 0; n < 4; ++n){
      size_t off = (size_t)(b*2048 + bb*128 + wn + n*16 + lm)*128 + (ks*32 + quad*8)*2;
      bh[n] = *(const bf16x8*)(Bhg + off);
      bl[n] = *(const bf16x8*)(Blg + off);
    }
    #pragma unroll
    for (int m = 0; m < 4; ++m){
      size_t off = (size_t)(b*2048 + a*128 + wm + m*16 + lm)*128 + (ks*32 + quad*8)*2;
      bf16x8 ah = *(const bf16x8*)(Ahg + off);
      bf16x8 al = *(const bf16x8*)(Alg + off);
      #pragma unroll
      for (int n = 0; n < 4; ++n){
        acc[m][n] = MFMA16(ah, bh[n], acc[m][n]);
        acc[m][n] = MFMA16(ah, bl[n], acc[m][n]);
        acc[m][n] = MFMA16(al, bh[n], acc[m][n]);
      }
    }
  }
  // swizzled 128x128 f16 tile: byte ^= (row&7)<<4
  #pragma unroll
  for (int m = 0; m < 4; ++m){
    #pragma unroll
    for (int n = 0; n < 4; ++n){
      #pragma unroll
      for (int e = 0; e < 4; ++e){
        int il = wm + m*16 + quad*4 + e;
        int jl = wn + n*16 + lm;
        int gi = a*128 + il, gj = bb*128 + jl;
        float v = acc[m][n][e];
        float outv;
        if (isSig) outv = (gj >  gi) ? (1.0f/(1.0f + __expf(-v*0.125f))) : 0.0f;
        else       outv = (gj <= gi) ? v : 0.0f;   // raw (unscaled) diag t1
        *(_Float16*)(sm + ((il*256 + jl*2) ^ ((il & 7) << 4))) = (_Float16)outv;
      }
    }
  }
  __syncthreads();
  char* outp = isSig
    ? (char*)(sg + (size_t)b*4194304 + (size_t)(a*128)*2048 + bb*128)
    : (char*)t1d + (size_t)(b*16 + a)*32768;
  size_t rstride = isSig ? 4096 : 256;       // bytes per row in dest
  #pragma unroll
  for (int r = 0; r < 8; ++r){
    int lrow = w*32 + r*4 + (lane >> 4);
    int c16 = lane & 15;
    f32x4 vv = *(const f32x4*)(sm + ((lrow*256 + c16*16) ^ ((lrow & 7) << 4)));
    *(f32x4*)(outp + (size_t)lrow*rstride + c16*16) = vv;
  }
  // fused W-GEMM: W[(c=bb,ck=a)] = sig_tile (LDS) @ Vu^T[bb], 128k x 64d, K=128 fp16 h/l
  if (isSig){
    int wm2 = (w & 1)*64, wn2 = (w >> 1)*32;
    f32x4 acc2[4][2] = {};
    #pragma unroll
    for (int ks = 0; ks < 4; ++ks){
      f16x8 bh2[2], bl2[2];
      #pragma unroll
      for (int n = 0; n < 2; ++n){
        int d = wn2 + n*16 + lm;
        size_t jo = ((size_t)(b*64 + d)*2048 + bb*128 + ks*32 + quad*8)*2;
        bh2[n] = *(const f16x8*)((const char*)vuth + jo);
        bl2[n] = *(const f16x8*)((const char*)vutl + jo);
      }
      #pragma unroll
      for (int m = 0; m < 4; ++m){
        int k = wm2 + m*16 + lm;
        f16x8 af = *(const f16x8*)(sm + ((k*256 + ks*64 + quad*16) ^ ((k & 7) << 4)));
        #pragma unroll
        for (int n = 0; n < 2; ++n){
          acc2[m][n] = MFMAF16(af, bh2[n], acc2[m][n]);
          acc2[m][n] = MFMAF16(af, bl2[n], acc2[m][n]);
        }
      }
    }
    float* Wp = W + (size_t)(b*136 + bb*(bb+1)/2 + a)*8192;
    #pragma unroll
    for (int m = 0; m < 4; ++m)
      #pragma unroll
      for (int n = 0; n < 2; ++n)
        #pragma unroll
        for (int e = 0; e < 4; ++e){
          int r = wm2 + m*16 + quad*4 + e;
          int col = wn2 + n*16 + lm;
          Wp[r*64 + col] = acc2[m][n][e];
        }
  }
}

// ---------------- P2b: parallel prefix P[ci][ck] = sum_{c in [ck,ci)} W[c][ck] -> bf16 h/l ----------------
__global__ __launch_bounds__(256) void k_scan(const float* __restrict__ W,
    unsigned short* __restrict__ Ph, unsigned short* __restrict__ Pl){
  int g = blockIdx.x, b = blockIdx.y;
  int ck = g >> 2, ksub = g & 3;
  if (ck >= 15) return;                      // ck=15 feeds nothing
  int tid = threadIdx.x;
  int rl = ksub*32 + (tid >> 3);             // row within 128-row chunk
  int col = (tid & 7)*8;
  float acc[8] = {};
  #pragma unroll 1
  for (int c = ck; c < 15; ++c){
    const float* wt = W + (size_t)(b*136 + c*(c+1)/2 + ck)*8192 + rl*64 + col;
    f32x4 v0 = *(const f32x4*)wt;
    f32x4 v1 = *(const f32x4*)(wt + 4);
    #pragma unroll
    for (int e = 0; e < 4; ++e){ acc[e] += v0[e]; acc[4+e] += v1[e]; }
    size_t o = ((size_t)(b*16 + c + 1)*2048 + ck*128 + rl)*64 + col;
    bf16x8 h, l;
    #pragma unroll
    for (int e = 0; e < 8; ++e){
      short hs = f2bf(acc[e]);
      h[e] = hs;
      l[e] = f2bf(acc[e] - bf2f(hs));
    }
    *(bf16x8*)(Ph + o) = h;
    *(bf16x8*)(Pl + o) = l;
  }
}

// ---------------- P3: flash-decoding PARTIAL per (ci,ck) tile ----------------
// One block per tile (grid 136x4, XCD-swizzled): logits (verbatim R9 k_p3), per-row
// tile-max, P=exp(L-m), PV MFMA -> partial O (128x64 f32) + per-row (m,l). k_mrg combines.
// R11 bug: ml aliased W/Op's 1MB spill into the xl region -> moved to its own region.
__global__ __launch_bounds__(256,2) void k_p3p(
    const unsigned short* __restrict__ ph, const unsigned short* __restrict__ pl,
    const _Float16* __restrict__ t1d, const _Float16* __restrict__ sg,
    const unsigned short* __restrict__ Ph, const unsigned short* __restrict__ Pl,
    const _Float16* __restrict__ vct, float* __restrict__ Op, float* __restrict__ ml){
  __shared__ __align__(16) char sm[32768];   // 128x128 f16 logits tile (XOR-swizzled)
  __shared__ float M2s[2][128], Mld[128], S2[128];
  int t0 = blockIdx.x, b = blockIdx.y;
  int t = (t0 & 7)*17 + (t0 >> 3);           // XCD-aware swizzle (136 = 8 XCD x 17)
  int ci = 0, ck = 0;
  #pragma unroll 1
  for (int aa = 0; aa < 16; ++aa){
    if (t < aa + 1){ ci = aa; ck = t; break; }
    t -= aa + 1;
  }
  int pair = ci*(ci+1)/2 + ck;
  int tid = threadIdx.x, w = tid >> 6, lane = tid & 63;
  int lm = lane & 15, quad = lane >> 4;
  int wm = (w & 1)*64, wn = (w >> 1)*64;
  f32x4 su[4][4] = {}, sc[4][4] = {};
  bool hasP = (ck < ci);

  const char* Qh = (const char*)ph + (size_t)3*1048576;
  const char* Ql = (const char*)pl + (size_t)3*1048576;
  const char* Kh = (const char*)ph + (size_t)4*1048576;
  const char* Kl = (const char*)pl + (size_t)4*1048576;
  const char* t1b = (const char*)t1d + (size_t)(b*16 + ci)*32768;
  const char* sgb = (const char*)sg + (size_t)b*8388608;
  const _Float16* vb = vct + (size_t)b*131072;

  // ---- merged: S_c = Qc @ Kc^T  and  rank-64 su = Qc @ P[ci]^T (shared Q-frags) ----
  #pragma unroll
  for (int ks = 0; ks < 2; ++ks){
    bf16x8 kh[4], kl[4], bh[4], bl[4];
    #pragma unroll
    for (int n = 0; n < 4; ++n){
      size_t offk = (size_t)(b*2048 + ck*128 + wn + n*16 + lm)*128 + (ks*32 + quad*8)*2;
      kh[n] = *(const bf16x8*)(Kh + offk);
      kl[n] = *(const bf16x8*)(Kl + offk);
    }
    if (hasP){
      #pragma unroll
      for (int n = 0; n < 4; ++n){
        size_t offp = (((size_t)(b*16 + ci)*2048 + ck*128 + wn + n*16 + lm)*64 + ks*32 + quad*8)*2;
        bh[n] = *(const bf16x8*)((const char*)Ph + offp);
        bl[n] = *(const bf16x8*)((const char*)Pl + offp);
      }
    }
    #pragma unroll
    for (int m = 0; m < 4; ++m){
      size_t offq = (size_t)(b*2048 + ci*128 + wm + m*16 + lm)*128 + (ks*32 + quad*8)*2;
      bf16x8 ah = *(const bf16x8*)(Qh + offq);
      bf16x8 al = *(const bf16x8*)(Ql + offq);
      #pragma unroll
      for (int n = 0; n < 4; ++n){
        sc[m][n] = MFMA16(ah, kh[n], sc[m][n]);
        sc[m][n] = MFMA16(ah, kl[n], sc[m][n]);
        sc[m][n] = MFMA16(al, kh[n], sc[m][n]);
      }
      if (hasP){
        #pragma unroll
        for (int n = 0; n < 4; ++n){
          su[m][n] = MFMA16(ah, bh[n], su[m][n]);
          su[m][n] = MFMA16(ah, bl[n], su[m][n]);
          su[m][n] = MFMA16(al, bh[n], su[m][n]);
        }
      }
    }
  }
  // ---- diag correction: t1d[ci] @ sig[ck-rows, ci-cols]^T (K=128 fp16) ----
  #pragma unroll
  for (int ks = 0; ks < 4; ++ks){
    f16x8 bs[4];
    #pragma unroll
    for (int n = 0; n < 4; ++n)
      bs[n] = *(const f16x8*)(sgb + ((size_t)(ck*128 + wn + n*16 + lm)*2048 + ci*128 + ks*32 + quad*8)*2);
    #pragma unroll
    for (int m = 0; m < 4; ++m){
      f16x8 at = *(const f16x8*)(t1b + ((wm + m*16 + lm)*128 + ks*32 + quad*8)*2);
      #pragma unroll
      for (int n = 0; n < 4; ++n)
        su[m][n] = MFMAF16(at, bs[n], su[m][n]);
    }
  }
  // ---- epilogue: masked logits -> LDS (swizzled) + per-row tile-max ----
  bool diag = (ck == ci);
  #pragma unroll
  for (int m = 0; m < 4; ++m){
    f32x4 hm = { -3.0e38f, -3.0e38f, -3.0e38f, -3.0e38f };
    #pragma unroll
    for (int n = 0; n < 4; ++n){
      #pragma unroll
      for (int e = 0; e < 4; ++e){
        int il = wm + m*16 + quad*4 + e;
        int jl = wn + n*16 + lm;
        float xv = 0.125f*su[m][n][e];
        float sg1 = 1.0f/(1.0f + __expf(-xv));
        float val = sc[m][n][e]*0.125f - xv*sg1;
        bool keep = !diag || (jl <= il);
        *(_Float16*)(sm + ((il*256 + jl*2) ^ ((il & 7) << 4))) =
            keep ? (_Float16)val : (_Float16)(-65504.0f);
        if (keep) hm[e] = fmaxf(hm[e], val);
      }
    }
    #pragma unroll
    for (int e = 0; e < 4; ++e){
      float v = hm[e];
      v = fmaxf(v, __shfl_xor(v, 1));
      v = fmaxf(v, __shfl_xor(v, 2));
      v = fmaxf(v, __shfl_xor(v, 4));
      v = fmaxf(v, __shfl_xor(v, 8));
      if (lm == 0) M2s[wn >> 6][wm + m*16 + quad*4 + e] = v;
    }
  }
  __syncthreads();                            // logits + M2s visible
  if (tid < 128) Mld[tid] = fmaxf(M2s[0][tid], M2s[1][tid]);
  __syncthreads();                            // Mld visible
  // ---- PV: P=exp(L-m_tile), MFMA accumulate, row-sum ----
  float mr0 = Mld[w*32 + lm], mr1 = Mld[w*32 + 16 + lm];
  float s0 = 0.0f, s1 = 0.0f;
  f32x4 Ov[2][4] = {};
  #pragma unroll
  for (int ks = 0; ks < 4; ++ks){
    f16x8 bv[4];
    #pragma unroll
    for (int n = 0; n < 4; ++n)
      bv[n] = *(const f16x8*)(vb + (size_t)(n*16 + lm)*2048 + ck*128 + ks*32 + quad*8);
    #pragma unroll
    for (int m2 = 0; m2 < 2; ++m2){
      int r = w*32 + m2*16 + lm;
      f16x8 Lv = *(const f16x8*)(sm + ((r*256 + ks*64 + quad*16) ^ ((r & 7) << 4)));
      float mrr = m2 ? mr1 : mr0;
      f16x8 af;
      #pragma unroll
      for (int e = 0; e < 8; ++e){
        float p = __expf((float)Lv[e] - mrr);
        if (m2) s1 += p; else s0 += p;
        af[e] = (_Float16)p;
      }
      #pragma unroll
      for (int n = 0; n < 4; ++n)
        Ov[m2][n] = MFMAF16(af, bv[n], Ov[m2][n]);
    }
  }
  s0 += __shfl_xor(s0, 16); s0 += __shfl_xor(s0, 32);
  s1 += __shfl_xor(s1, 16); s1 += __shfl_xor(s1, 32);
  if (quad == 0){ S2[w*32 + lm] = s0; S2[w*32 + 16 + lm] = s1; }
  __syncthreads();                            // S2 visible
  // ---- write partials ----
  float* Opp = Op + (size_t)(b*136 + pair)*8192;
  #pragma unroll
  for (int m2 = 0; m2 < 2; ++m2)
    #pragma unroll
    for (int e = 0; e < 4; ++e){
      int r = w*32 + m2*16 + quad*4 + e;
      #pragma unroll
      for (int n = 0; n < 4; ++n)
        Opp[r*64 + n*16 + lm] = Ov[m2][n][e];
    }
  if (tid < 128){
    size_t mo = (size_t)(b*136 + pair)*256;
    ml[mo + tid] = Mld[tid];
    ml[mo + 128 + tid] = S2[tid];
  }
}

// ---------------- P4: merge partials (streaming) ----------------
__global__ __launch_bounds__(256) void k_mrg(const float* __restrict__ Op,
    const float* __restrict__ ml, float* __restrict__ out){
  int ci = blockIdx.x, b = blockIdx.y;
  int tid = threadIdx.x;
  int r = tid >> 1, half = tid & 1;
  int base = ci*(ci+1)/2;
  float M = -3.0e38f;
  #pragma unroll 1
  for (int ck = 0; ck <= ci; ++ck)
    M = fmaxf(M, ml[(size_t)(b*136 + base + ck)*256 + r]);
  float lt = 0.0f;
  f32x4 O[8] = {};
  #pragma unroll 1
  for (int ck = 0; ck <= ci; ++ck){
    size_t mo = (size_t)(b*136 + base + ck)*256;
    float f = __expf(ml[mo + r] - M);
    lt += f * ml[mo + 128 + r];
    const float* op = Op + (size_t)(b*136 + base + ck)*8192 + r*64 + half*32;
    #pragma unroll
    for (int j = 0; j < 8; ++j){
      f32x4 v = *(const f32x4*)(op + j*4);
      O[j][0] += f*v[0]; O[j][1] += f*v[1]; O[j][2] += f*v[2]; O[j][3] += f*v[3];
    }
  }
  float* ob = out + ((size_t)b*2048 + ci*128 + r)*64 + half*32;
  #pragma unroll
  for (int j = 0; j < 8; ++j){
    f32x4 v = { O[j][0]/lt, O[j][1]/lt, O[j][2]/lt, O[j][3]/lt };
    *(f32x4*)(ob + j*4) = v;
  }
}

// ---------------- workspace layout (bytes) ----------------
static const size_t OFF_WTH   = 4194304;     // 6 x 64x1024 bf16
static const size_t OFF_WTL   = 4980736;
static const size_t OFF_PROJH = 5767168;     // 6 x 8192x64 bf16
static const size_t OFF_PROJL = 12058624;
static const size_t OFF_VCT   = 18350080;    // 4 x 64x2048 f16
static const size_t OFF_SG    = 19398656;    // 4 x 2048^2 f16
static const size_t OFF_T1D   = 86507520;    // 4 x 16 x 128x128 f16
static const size_t OFF_PH    = 88604672;    // 4 x 16 x 2048x64 bf16
static const size_t OFF_PL    = 105381888;
static const size_t OFF_VUTH  = 122159104;   // 4 x 64x2048 f16
static const size_t OFF_VUTL  = 123207680;
static const size_t OFF_XH    = 124256256;   // 8192x1024 bf16
static const size_t OFF_XL    = 141033472;
// W/Op (4 x 136 x 128x64 f32 = 17,825,792 B) reuses xh (dead after k_proj) and spills
// ~1MB into the START of xl (also dead). ml gets its OWN region past xl's end —
// R11 bug: ml at OFF_XL aliased that spill (batch-3 Op partials stomped m/l).
static const size_t OFF_W     = OFF_XH;
static const size_t OFF_OP    = OFF_XH;
static const size_t OFF_ML    = 157810688;   // 4 x 136 x 256 f32 = 557,056 B
// total = 158,367,744 bytes

extern "C" void kernel_launch(void* const* d_in, const int* in_sizes, int n_in,
                              void* d_out, int out_size, void* d_ws, size_t ws_size,
                              hipStream_t stream){
  (void)in_sizes; (void)n_in; (void)out_size; (void)ws_size;
  const float* x = (const float*)d_in[0];
  char* ws = (char*)d_ws;
  unsigned short* wth   = (unsigned short*)(ws + OFF_WTH);
  unsigned short* wtl   = (unsigned short*)(ws + OFF_WTL);
  unsigned short* projh = (unsigned short*)(ws + OFF_PROJH);
  unsigned short* projl = (unsigned short*)(ws + OFF_PROJL);
  _Float16*       vct   = (_Float16*)(ws + OFF_VCT);
  _Float16*       sg    = (_Float16*)(ws + OFF_SG);
  _Float16*       t1d   = (_Float16*)(ws + OFF_T1D);
  unsigned short* Phb   = (unsigned short*)(ws + OFF_PH);
  unsigned short* Plb   = (unsigned short*)(ws + OFF_PL);
  _Float16*       vuth  = (_Float16*)(ws + OFF_VUTH);
  _Float16*       vutl  = (_Float16*)(ws + OFF_VUTL);
  unsigned short* xh    = (unsigned short*)(ws + OFF_XH);
  unsigned short* xl    = (unsigned short*)(ws + OFF_XL);
  float*          Wb    = (float*)(ws + OFF_W);
  float*          Opb   = (float*)(ws + OFF_OP);
  float*          mlb   = (float*)(ws + OFF_ML);

  k_prep  <<<dim3(5632),   256, 0, stream>>>((const float*)d_in[1], (const float*)d_in[2],
                                             (const float*)d_in[3], (const float*)d_in[4],
                                             (const float*)d_in[5], (const float*)d_in[6],
                                             x, wth, wtl, xh, xl);
  k_proj  <<<dim3(384),    256, 0, stream>>>(xh, xl, wth, wtl, projh, projl, vct, vuth, vutl);
  k_p2    <<<dim3(152,4),  256, 0, stream>>>(projh, projl, vuth, vutl, sg, t1d, Wb);
  k_scan  <<<dim3(64,4),   256, 0, stream>>>(Wb, Phb, Plb);
  k_p3p   <<<dim3(136,4),  256, 0, stream>>>(projh, projl, t1d, sg, Phb, Plb, vct, Opb, mlb);
  k_mrg   <<<dim3(16,4),   256, 0, stream>>>(Opb, mlb, (float*)d_out);
}

// Round 13
// 204.008 us; speedup vs baseline: 1.9354x; 1.1067x over previous
//
#include <hip/hip_runtime.h>
#include <hip/hip_bf16.h>

// B=4, S=2048, D=1024, DH=64. Inputs/outputs are FLOAT32 (per reference).
typedef short bf16x8 __attribute__((ext_vector_type(8)));
typedef float f32x4  __attribute__((ext_vector_type(4)));
typedef _Float16 f16x8 __attribute__((ext_vector_type(8)));

#define MFMA16(a,b,c)  __builtin_amdgcn_mfma_f32_16x16x32_bf16((a),(b),(c),0,0,0)
#define MFMAF16(a,b,c) __builtin_amdgcn_mfma_f32_16x16x32_f16((a),(b),(c),0,0,0)

// async global->LDS: 16B per lane, lane i lands at lds_base + i*16
#define GLDS16(g,l) __builtin_amdgcn_global_load_lds( \
    (const __attribute__((address_space(1))) void*)(g), \
    (__attribute__((address_space(3))) void*)(l), 16, 0, 0)

__device__ __forceinline__ short f2bf(float f){
  union { float f; unsigned u; } v; v.f = f;
  unsigned r = v.u + 0x7fffu + ((v.u >> 16) & 1u);
  return (short)(r >> 16);
}
__device__ __forceinline__ float bf2f(short h){
  union { unsigned u; float f; } v; v.u = ((unsigned)(unsigned short)h) << 16;
  return v.f;
}
__device__ __forceinline__ void split8v(f32x4 a, f32x4 b, bf16x8& h, bf16x8& l){
  float t[8] = {a[0],a[1],a[2],a[3],b[0],b[1],b[2],b[3]};
  #pragma unroll
  for (int e = 0; e < 8; ++e){
    short hs = f2bf(t[e]);
    h[e] = hs;
    l[e] = f2bf(t[e] - bf2f(hs));
  }
}

// ---------------- P0 (fused): weight transpose+split (blocks 0..1535) + x split (1536..5631) ----------------
__global__ void k_prep(const float* w0, const float* w1, const float* w2,
                       const float* w3, const float* w4, const float* w5,
                       const float* __restrict__ x,
                       unsigned short* __restrict__ wth, unsigned short* __restrict__ wtl,
                       unsigned short* __restrict__ xh, unsigned short* __restrict__ xl){
  int gb = blockIdx.x;
  if (gb < 1536){
    int p = gb >> 8;
    const float* wp = p==0?w0:p==1?w1:p==2?w2:p==3?w3:p==4?w4:w5;
    int idx = (gb & 255)*256 + threadIdx.x;   // [0,65536)
    int n = idx >> 10, k = idx & 1023;
    float v = wp[k*64 + n];
    short hs = f2bf(v);
    wth[(size_t)p*65536 + n*1024 + k] = (unsigned short)hs;
    wtl[(size_t)p*65536 + n*1024 + k] = (unsigned short)f2bf(v - bf2f(hs));
  } else {
    size_t i = ((size_t)(gb - 1536)*256 + threadIdx.x)*8;
    f32x4 a = *(const f32x4*)(x + i);
    f32x4 b = *(const f32x4*)(x + i + 4);
    bf16x8 h, l;
    split8v(a, b, h, l);
    *(bf16x8*)(xh + i) = h;
    *(bf16x8*)(xl + i) = l;
  }
}

// ---------------- P1: projections + fused V-transpose epilogue ----------------
__global__ __launch_bounds__(256) void k_proj(
    const unsigned short* __restrict__ xh, const unsigned short* __restrict__ xl,
    const unsigned short* __restrict__ wth, const unsigned short* __restrict__ wtl,
    unsigned short* __restrict__ projh, unsigned short* __restrict__ projl,
    _Float16* __restrict__ vct, _Float16* __restrict__ vuth, _Float16* __restrict__ vutl){
  __shared__ __align__(16) char sm[49152];  // xh 8K | xl 8K | w0h 8K | w0l 8K | w1h 8K | w1l 8K
  int blk = blockIdx.x;
  int rb = blk/3, pg = blk - rb*3;
  int tid = threadIdx.x, w = tid >> 6, lane = tid & 63;
  int lm = lane & 15, quad = lane >> 4;
  int srow = lane >> 3, scg = (lane & 7) ^ srow;
  const char* xhg = (const char*)xh;
  const char* xlg = (const char*)xl;
  const char* w0h = (const char*)wth + (size_t)(pg*2  )*131072;
  const char* w0l = (const char*)wtl + (size_t)(pg*2  )*131072;
  const char* w1h = (const char*)wth + (size_t)(pg*2+1)*131072;
  const char* w1l = (const char*)wtl + (size_t)(pg*2+1)*131072;
  f32x4 acc[2][4] = {};
  for (int k0 = 0; k0 < 1024; k0 += 64){
    __syncthreads();
    size_t cb = (size_t)k0*2 + scg*16;
    #pragma unroll
    for (int i2 = 0; i2 < 2; ++i2){
      int i = w*2 + i2;
      size_t gx = (size_t)(rb*64 + i*8 + srow)*2048 + cb;
      size_t gw = (size_t)(i*8 + srow)*2048 + cb;
      GLDS16(xhg + gx, sm +         i*1024);
      GLDS16(xlg + gx, sm +  8192 + i*1024);
      GLDS16(w0h + gw, sm + 16384 + i*1024);
      GLDS16(w0l + gw, sm + 24576 + i*1024);
      GLDS16(w1h + gw, sm + 32768 + i*1024);
      GLDS16(w1l + gw, sm + 40960 + i*1024);
    }
    __syncthreads();
    #pragma unroll
    for (int ks = 0; ks < 2; ++ks){
      int ra = w*16 + lm;
      int offa = ra*128 + (((ks*4+quad) ^ (ra&7))*16);
      bf16x8 ah = *(const bf16x8*)(sm + offa);
      bf16x8 al = *(const bf16x8*)(sm + 8192 + offa);
      #pragma unroll
      for (int sub = 0; sub < 2; ++sub){
        #pragma unroll
        for (int n = 0; n < 4; ++n){
          int r = n*16 + lm;
          int off = r*128 + (((ks*4+quad) ^ (r&7))*16);
          bf16x8 bh = *(const bf16x8*)(sm + 16384 + sub*16384 + off);
          bf16x8 bl = *(const bf16x8*)(sm + 24576 + sub*16384 + off);
          acc[sub][n] = MFMA16(ah, bh, acc[sub][n]);
          acc[sub][n] = MFMA16(ah, bl, acc[sub][n]);
          acc[sub][n] = MFMA16(al, bh, acc[sub][n]);
        }
      }
    }
  }
  #pragma unroll
  for (int sub = 0; sub < 2; ++sub){
    int p = pg*2 + sub;
    if (p != 5){
      unsigned short* oph = projh + (size_t)p*524288;
      unsigned short* opl = projl + (size_t)p*524288;
      #pragma unroll
      for (int n = 0; n < 4; ++n)
        #pragma unroll
        for (int e = 0; e < 4; ++e){
          int r = rb*64 + w*16 + quad*4 + e;
          float f = acc[sub][n][e];
          short hs = f2bf(f);
          oph[(size_t)r*64 + n*16 + lm] = (unsigned short)hs;
          opl[(size_t)r*64 + n*16 + lm] = (unsigned short)f2bf(f - bf2f(hs));
        }
    }
  }
  // fused transpose: pg==1 -> Vu (sub 0) to vuth/vutl; pg==2 -> Vc (sub 1) to vct
  if (pg == 1 || pg == 2){
    int sub = (pg == 1) ? 0 : 1;
    float (*T)[65] = (float (*)[65])sm;
    __syncthreads();                          // main-loop LDS reads done
    #pragma unroll
    for (int n = 0; n < 4; ++n)
      #pragma unroll
      for (int e = 0; e < 4; ++e)
        T[w*16 + quad*4 + e][n*16 + lm] = acc[sub][n][e];
    __syncthreads();
    int b2 = rb >> 5, sl = (rb & 31)*64;
    int d = tid >> 2, sp = (tid & 3)*16;
    size_t o = (size_t)b2*131072 + (size_t)d*2048 + sl + sp;
    if (sub == 1){
      f16x8 h0, h1;
      #pragma unroll
      for (int j = 0; j < 8; ++j) h0[j] = (_Float16)T[sp + j][d];
      #pragma unroll
      for (int j = 0; j < 8; ++j) h1[j] = (_Float16)T[sp + 8 + j][d];
      *(f16x8*)(vct + o) = h0; *(f16x8*)(vct + o + 8) = h1;
    } else {
      f16x8 h0, h1, l0, l1;
      #pragma unroll
      for (int j = 0; j < 8; ++j){
        float f = T[sp + j][d];
        _Float16 h = (_Float16)f;
        h0[j] = h; l0[j] = (_Float16)(f - (float)h);
      }
      #pragma unroll
      for (int j = 0; j < 8; ++j){
        float f = T[sp + 8 + j][d];
        _Float16 h = (_Float16)f;
        h1[j] = h; l1[j] = (_Float16)(f - (float)h);
      }
      *(f16x8*)(vuth + o) = h0; *(f16x8*)(vuth + o + 8) = h1;
      *(f16x8*)(vutl + o) = l0; *(f16x8*)(vutl + o + 8) = l1;
    }
  }
}

// ---------------- P2: sig tiles (136) + diag t1 tiles (16), FUSED W-GEMM, direct loads ----------------
__global__ __launch_bounds__(256,3) void k_p2(
    const unsigned short* __restrict__ ph, const unsigned short* __restrict__ pl,
    const _Float16* __restrict__ vuth, const _Float16* __restrict__ vutl,
    _Float16* __restrict__ sg, _Float16* __restrict__ t1d, float* __restrict__ W){
  __shared__ __align__(16) char sm[32768];   // 128x128 f16 tile (XOR-swizzled)
  int b = blockIdx.y;
  int t = blockIdx.x;                        // [0,152): 136 sig + 16 diag-t1
  bool isSig = t < 136;
  int a = 0, bb = 0;
  if (isSig){
    #pragma unroll 1
    for (int aa = 0; aa < 16; ++aa){
      int c = 16 - aa;
      if (t < c){ a = aa; bb = aa + t; break; }
      t -= c;
    }
  } else {
    a = bb = t - 136;
  }
  int pa = isSig ? 0 : 3;                    // A = Qu : Qc
  int pb = isSig ? 1 : 2;                    // B = Ku : Vu
  const char* Ahg = (const char*)ph + (size_t)pa*1048576;
  const char* Alg = (const char*)pl + (size_t)pa*1048576;
  const char* Bhg = (const char*)ph + (size_t)pb*1048576;
  const char* Blg = (const char*)pl + (size_t)pb*1048576;
  int tid = threadIdx.x, w = tid >> 6, lane = tid & 63;
  int lm = lane & 15, quad = lane >> 4;
  int wm = (w & 1)*64, wn = (w >> 1)*64;
  f32x4 acc[4][4] = {};
  #pragma unroll
  for (int ks = 0; ks < 2; ++ks){
    bf16x8 bh[4], bl[4];
    #pragma unroll
    for (int n = 0; n < 4; ++n){
      size_t off = (size_t)(b*2048 + bb*128 + wn + n*16 + lm)*128 + (ks*32 + quad*8)*2;
      bh[n] = *(const bf16x8*)(Bhg + off);
      bl[n] = *(const bf16x8*)(Blg + off);
    }
    #pragma unroll
    for (int m = 0; m < 4; ++m){
      size_t off = (size_t)(b*2048 + a*128 + wm + m*16 + lm)*128 + (ks*32 + quad*8)*2;
      bf16x8 ah = *(const bf16x8*)(Ahg + off);
      bf16x8 al = *(const bf16x8*)(Alg + off);
      #pragma unroll
      for (int n = 0; n < 4; ++n){
        acc[m][n] = MFMA16(ah, bh[n], acc[m][n]);
        acc[m][n] = MFMA16(ah, bl[n], acc[m][n]);
        acc[m][n] = MFMA16(al, bh[n], acc[m][n]);
      }
    }
  }
  // swizzled 128x128 f16 tile: byte ^= (row&7)<<4
  #pragma unroll
  for (int m = 0; m < 4; ++m){
    #pragma unroll
    for (int n = 0; n < 4; ++n){
      #pragma unroll
      for (int e = 0; e < 4; ++e){
        int il = wm + m*16 + quad*4 + e;
        int jl = wn + n*16 + lm;
        int gi = a*128 + il, gj = bb*128 + jl;
        float v = acc[m][n][e];
        float outv;
        if (isSig) outv = (gj >  gi) ? (1.0f/(1.0f + __expf(-v*0.125f))) : 0.0f;
        else       outv = (gj <= gi) ? v : 0.0f;   // raw (unscaled) diag t1
        *(_Float16*)(sm + ((il*256 + jl*2) ^ ((il & 7) << 4))) = (_Float16)outv;
      }
    }
  }
  __syncthreads();
  char* outp = isSig
    ? (char*)(sg + (size_t)b*4194304 + (size_t)(a*128)*2048 + bb*128)
    : (char*)t1d + (size_t)(b*16 + a)*32768;
  size_t rstride = isSig ? 4096 : 256;       // bytes per row in dest
  #pragma unroll
  for (int r = 0; r < 8; ++r){
    int lrow = w*32 + r*4 + (lane >> 4);
    int c16 = lane & 15;
    f32x4 vv = *(const f32x4*)(sm + ((lrow*256 + c16*16) ^ ((lrow & 7) << 4)));
    *(f32x4*)(outp + (size_t)lrow*rstride + c16*16) = vv;
  }
  // fused W-GEMM: W[(c=bb,ck=a)] = sig_tile (LDS) @ Vu^T[bb], 128k x 64d, K=128 fp16 h/l
  if (isSig){
    int wm2 = (w & 1)*64, wn2 = (w >> 1)*32;
    f32x4 acc2[4][2] = {};
    #pragma unroll
    for (int ks = 0; ks < 4; ++ks){
      f16x8 bh2[2], bl2[2];
      #pragma unroll
      for (int n = 0; n < 2; ++n){
        int d = wn2 + n*16 + lm;
        size_t jo = ((size_t)(b*64 + d)*2048 + bb*128 + ks*32 + quad*8)*2;
        bh2[n] = *(const f16x8*)((const char*)vuth + jo);
        bl2[n] = *(const f16x8*)((const char*)vutl + jo);
      }
      #pragma unroll
      for (int m = 0; m < 4; ++m){
        int k = wm2 + m*16 + lm;
        f16x8 af = *(const f16x8*)(sm + ((k*256 + ks*64 + quad*16) ^ ((k & 7) << 4)));
        #pragma unroll
        for (int n = 0; n < 2; ++n){
          acc2[m][n] = MFMAF16(af, bh2[n], acc2[m][n]);
          acc2[m][n] = MFMAF16(af, bl2[n], acc2[m][n]);
        }
      }
    }
    float* Wp = W + (size_t)(b*136 + bb*(bb+1)/2 + a)*8192;
    #pragma unroll
    for (int m = 0; m < 4; ++m)
      #pragma unroll
      for (int n = 0; n < 2; ++n)
        #pragma unroll
        for (int e = 0; e < 4; ++e){
          int r = wm2 + m*16 + quad*4 + e;
          int col = wn2 + n*16 + lm;
          Wp[r*64 + col] = acc2[m][n][e];
        }
  }
}

// ---------------- P2b: parallel prefix P[ci][ck] = sum_{c in [ck,ci)} W[c][ck] -> bf16 h/l ----------------
__global__ __launch_bounds__(256) void k_scan(const float* __restrict__ W,
    unsigned short* __restrict__ Ph, unsigned short* __restrict__ Pl){
  int g = blockIdx.x, b = blockIdx.y;
  int ck = g >> 2, ksub = g & 3;
  if (ck >= 15) return;                      // ck=15 feeds nothing
  int tid = threadIdx.x;
  int rl = ksub*32 + (tid >> 3);             // row within 128-row chunk
  int col = (tid & 7)*8;
  float acc[8] = {};
  #pragma unroll 1
  for (int c = ck; c < 15; ++c){
    const float* wt = W + (size_t)(b*136 + c*(c+1)/2 + ck)*8192 + rl*64 + col;
    f32x4 v0 = *(const f32x4*)wt;
    f32x4 v1 = *(const f32x4*)(wt + 4);
    #pragma unroll
    for (int e = 0; e < 4; ++e){ acc[e] += v0[e]; acc[4+e] += v1[e]; }
    size_t o = ((size_t)(b*16 + c + 1)*2048 + ck*128 + rl)*64 + col;
    bf16x8 h, l;
    #pragma unroll
    for (int e = 0; e < 8; ++e){
      short hs = f2bf(acc[e]);
      h[e] = hs;
      l[e] = f2bf(acc[e] - bf2f(hs));
    }
    *(bf16x8*)(Ph + o) = h;
    *(bf16x8*)(Pl + o) = l;
  }
}

// ---------------- P3: logits tile (ci,ck), full 128x128, shared Q-frags, XCD swizzle ----------------
__global__ __launch_bounds__(256,2) void k_p3(
    const unsigned short* __restrict__ ph, const unsigned short* __restrict__ pl,
    const _Float16* __restrict__ t1d, const _Float16* __restrict__ sg,
    const unsigned short* __restrict__ Ph, const unsigned short* __restrict__ Pl,
    _Float16* __restrict__ lg){
  __shared__ __align__(16) char sm[32768];   // 128x128 fp16 logits tile
  int t0 = blockIdx.x, b = blockIdx.y;
  int t = (t0 & 7)*17 + (t0 >> 3);           // XCD-aware swizzle (136 = 8 XCD x 17)
  int ci = 0, ck = 0;
  #pragma unroll 1
  for (int aa = 0; aa < 16; ++aa){
    if (t < aa + 1){ ci = aa; ck = t; break; }
    t -= aa + 1;
  }
  int tid = threadIdx.x, w = tid >> 6, lane = tid & 63;
  int lm = lane & 15, quad = lane >> 4;
  int wm = (w & 1)*64, wn = (w >> 1)*64;
  f32x4 su[4][4] = {}, sc[4][4] = {};
  bool hasP = (ck < ci);

  const char* Qh = (const char*)ph + (size_t)3*1048576;
  const char* Ql = (const char*)pl + (size_t)3*1048576;
  const char* Kh = (const char*)ph + (size_t)4*1048576;
  const char* Kl = (const char*)pl + (size_t)4*1048576;

  // ---- merged: S_c = Qc @ Kc^T  and  rank-64 su = Qc @ P[ci]^T (shared Q-frags) ----
  #pragma unroll
  for (int ks = 0; ks < 2; ++ks){
    bf16x8 kh[4], kl[4], bh[4], bl[4];
    #pragma unroll
    for (int n = 0; n < 4; ++n){
      size_t offk = (size_t)(b*2048 + ck*128 + wn + n*16 + lm)*128 + (ks*32 + quad*8)*2;
      kh[n] = *(const bf16x8*)(Kh + offk);
      kl[n] = *(const bf16x8*)(Kl + offk);
    }
    if (hasP){
      #pragma unroll
      for (int n = 0; n < 4; ++n){
        size_t offp = (((size_t)(b*16 + ci)*2048 + ck*128 + wn + n*16 + lm)*64 + ks*32 + quad*8)*2;
        bh[n] = *(const bf16x8*)((const char*)Ph + offp);
        bl[n] = *(const bf16x8*)((const char*)Pl + offp);
      }
    }
    #pragma unroll
    for (int m = 0; m < 4; ++m){
      size_t offq = (size_t)(b*2048 + ci*128 + wm + m*16 + lm)*128 + (ks*32 + quad*8)*2;
      bf16x8 ah = *(const bf16x8*)(Qh + offq);
      bf16x8 al = *(const bf16x8*)(Ql + offq);
      #pragma unroll
      for (int n = 0; n < 4; ++n){
        sc[m][n] = MFMA16(ah, kh[n], sc[m][n]);
        sc[m][n] = MFMA16(ah, kl[n], sc[m][n]);
        sc[m][n] = MFMA16(al, kh[n], sc[m][n]);
      }
      if (hasP){
        #pragma unroll
        for (int n = 0; n < 4; ++n){
          su[m][n] = MFMA16(ah, bh[n], su[m][n]);
          su[m][n] = MFMA16(ah, bl[n], su[m][n]);
          su[m][n] = MFMA16(al, bh[n], su[m][n]);
        }
      }
    }
  }
  // ---- diag correction: t1d[ci] @ sig[ck-rows, ci-cols]^T (K=128 fp16) ----
  const char* t1b = (const char*)t1d + (size_t)(b*16 + ci)*32768;
  const char* sgb = (const char*)sg + (size_t)b*8388608;
  #pragma unroll
  for (int ks = 0; ks < 4; ++ks){
    f16x8 bs[4];
    #pragma unroll
    for (int n = 0; n < 4; ++n)
      bs[n] = *(const f16x8*)(sgb + ((size_t)(ck*128 + wn + n*16 + lm)*2048 + ci*128 + ks*32 + quad*8)*2);
    #pragma unroll
    for (int m = 0; m < 4; ++m){
      f16x8 at = *(const f16x8*)(t1b + ((wm + m*16 + lm)*128 + ks*32 + quad*8)*2);
      #pragma unroll
      for (int n = 0; n < 4; ++n)
        su[m][n] = MFMAF16(at, bs[n], su[m][n]);
    }
  }
  // ---- epilogue ----
  _Float16* Tt = (_Float16*)sm;
  #pragma unroll
  for (int m = 0; m < 4; ++m)
    #pragma unroll
    for (int n = 0; n < 4; ++n)
      #pragma unroll
      for (int e = 0; e < 4; ++e){
        int il = wm + m*16 + quad*4 + e;
        int jl = wn + n*16 + lm;
        float xv = 0.125f*su[m][n][e];
        float sg1 = 1.0f/(1.0f + __expf(-xv));
        Tt[il*128 + jl] = (_Float16)(sc[m][n][e]*0.125f - xv*sg1);
      }
  __syncthreads();
  _Float16* lgb = lg + (size_t)b*4194304;
  #pragma unroll
  for (int r = 0; r < 8; ++r){
    int lrow = w*32 + r*4 + (lane >> 4);
    int c16 = lane & 15;
    f32x4 vv = *(const f32x4*)(sm + lrow*256 + c16*16);
    *(f32x4*)((char*)(lgb + (size_t)(ci*128 + lrow)*2048 + ck*128) + c16*16) = vv;
  }
}

// ---------------- P4 (fused): band softmax + P @ V_c, paired bands ----------------
// R13: sweep-2 (exp-sum) folded into the PV pass — identical element coverage (full
// chunks have all cols <= r0 <= row; masked p zeroed before the add), identical mfin
// (sweep-1 unchanged). Saves one 64KB LDS sweep + ~130 exp per lane per band.
__global__ __launch_bounds__(256,2) void k_p4(const _Float16* __restrict__ lg,
    const _Float16* __restrict__ vct, float* __restrict__ out){
  __shared__ __align__(16) char sm[66048];   // Ls 64K | Mz 256B | Sz 256B
  float* Mz = (float*)(sm + 65536);
  float* Sz = (float*)(sm + 65792);
  int b = blockIdx.y;
  int b1 = blockIdx.x;                       // 0..63; handles bands b1 and 127-b1
  int tid = threadIdx.x, w = tid >> 6, lane = tid & 63;
  int lm = lane & 15, quad = lane >> 4;
  const _Float16* vb = vct + (size_t)b*131072;
  for (int pass = 0; pass < 2; ++pass){
    int band = pass ? (127 - b1) : b1;
    int r0 = band*16;
    const char* lgb = (const char*)lg + ((size_t)b*4194304 + (size_t)r0*2048)*2;
    int nkt = ((r0 + 15) >> 6) + 1;
    int fc = (r0 + 1) >> 6;
    int srl = lane >> 3, ssl = lane & 7;
    __syncthreads();                          // LDS reuse vs previous pass
    for (int kt = w; kt < nkt; kt += 4){
      #pragma unroll
      for (int i2 = 0; i2 < 2; ++i2){
        int rl = i2*8 + srl;
        GLDS16(lgb + (size_t)rl*4096 + kt*128 + ((ssl ^ (rl & 7))*16),
               sm + kt*2048 + i2*1024);
      }
    }
    __syncthreads();
    // sweep 1: causal row max
    float m_r = -3.0e38f;
    for (int kt = w; kt < nkt; kt += 4){
      #pragma unroll
      for (int half = 0; half < 2; ++half){
        int sl = quad*2 + half;
        f16x8 v = *(const f16x8*)(sm + kt*2048 + lm*128 + ((sl ^ (lm & 7))*16));
        int cb = kt*64 + sl*8;
        #pragma unroll
        for (int e = 0; e < 8; ++e)
          m_r = (cb + e <= r0 + lm) ? fmaxf(m_r, (float)v[e]) : m_r;
      }
    }
    m_r = fmaxf(m_r, __shfl_xor(m_r, 16));
    m_r = fmaxf(m_r, __shfl_xor(m_r, 32));
    Mz[w*16 + lm] = m_r;
    __syncthreads();
    float mfin = fmaxf(fmaxf(Mz[lm], Mz[16 + lm]), fmaxf(Mz[32 + lm], Mz[48 + lm]));
    // single pass: P = exp(L - mfin) with sum folded in, PV MFMA
    float s_r = 0.0f;
    f32x4 acc[4] = {};
    for (int kt = w; kt < nkt; kt += 4){
      bool full = kt < fc;
      #pragma unroll
      for (int ks = 0; ks < 2; ++ks){
        f16x8 Lv = *(const f16x8*)(sm + kt*2048 + lm*128 + (((ks*4+quad) ^ (lm & 7))*16));
        int jbase = kt*64 + ks*32 + quad*8;
        f16x8 af;
        #pragma unroll
        for (int e = 0; e < 8; ++e){
          float p = __expf((float)Lv[e] - mfin);
          if (!full && (jbase + e > r0 + lm)) p = 0.0f;
          s_r += p;
          af[e] = (_Float16)p;
        }
        #pragma unroll
        for (int n = 0; n < 4; ++n){
          f16x8 bv = *(const f16x8*)(vb + (size_t)(n*16 + lm)*2048 + jbase);
          acc[n] = MFMAF16(af, bv, acc[n]);
        }
      }
    }
    s_r += __shfl_xor(s_r, 16);
    s_r += __shfl_xor(s_r, 32);
    Sz[w*16 + lm] = s_r;
    __syncthreads();
    float* Ot = (float*)sm;                  // [4][16][64], reuses dead Ls
    #pragma unroll
    for (int n = 0; n < 4; ++n)
      #pragma unroll
      for (int e = 0; e < 4; ++e)
        Ot[(w*16 + quad*4 + e)*64 + n*16 + lm] = acc[n][e];
    __syncthreads();
    int row = tid >> 4, c4 = (tid & 15)*4;
    f32x4 s = *(const f32x4*)&Ot[row*64 + c4];
    #pragma unroll
    for (int ww = 1; ww < 4; ++ww){
      f32x4 t2 = *(const f32x4*)&Ot[(ww*16 + row)*64 + c4];
      s[0]+=t2[0]; s[1]+=t2[1]; s[2]+=t2[2]; s[3]+=t2[3];
    }
    float z = Sz[row] + Sz[16 + row] + Sz[32 + row] + Sz[48 + row];
    f32x4 o = { s[0]/z, s[1]/z, s[2]/z, s[3]/z };
    *(f32x4*)(out + ((size_t)b*2048 + r0 + row)*64 + c4) = o;
  }
}

// ---------------- workspace layout (bytes) ----------------
static const size_t OFF_WTH   = 4194304;     // 6 x 64x1024 bf16
static const size_t OFF_WTL   = 4980736;
static const size_t OFF_PROJH = 5767168;     // 6 x 8192x64 bf16
static const size_t OFF_PROJL = 12058624;
static const size_t OFF_VCT   = 18350080;    // 4 x 64x2048 f16
static const size_t OFF_SG    = 19398656;    // 4 x 2048^2 f16
static const size_t OFF_LG    = 52953088;    // 4 x 2048^2 f16
static const size_t OFF_T1D   = 86507520;    // 4 x 16 x 128x128 f16
static const size_t OFF_PH    = 88604672;    // 4 x 16 x 2048x64 bf16
static const size_t OFF_PL    = 105381888;
static const size_t OFF_VUTH  = 122159104;   // 4 x 64x2048 f16
static const size_t OFF_VUTL  = 123207680;
static const size_t OFF_XH    = 124256256;   // 8192x1024 bf16
static const size_t OFF_XL    = 141033472;
// W (4 x 136 x 128x64 f32 = 17,825,792 B) reuses xh (dead after k_proj) and spills
// ~1MB into the start of xl (also dead by then).
static const size_t OFF_W     = OFF_XH;
// total = 157,810,688 bytes

extern "C" void kernel_launch(void* const* d_in, const int* in_sizes, int n_in,
                              void* d_out, int out_size, void* d_ws, size_t ws_size,
                              hipStream_t stream){
  (void)in_sizes; (void)n_in; (void)out_size; (void)ws_size;
  const float* x = (const float*)d_in[0];
  char* ws = (char*)d_ws;
  unsigned short* wth   = (unsigned short*)(ws + OFF_WTH);
  unsigned short* wtl   = (unsigned short*)(ws + OFF_WTL);
  unsigned short* projh = (unsigned short*)(ws + OFF_PROJH);
  unsigned short* projl = (unsigned short*)(ws + OFF_PROJL);
  _Float16*       vct   = (_Float16*)(ws + OFF_VCT);
  _Float16*       sg    = (_Float16*)(ws + OFF_SG);
  _Float16*       lg    = (_Float16*)(ws + OFF_LG);
  _Float16*       t1d   = (_Float16*)(ws + OFF_T1D);
  unsigned short* Phb   = (unsigned short*)(ws + OFF_PH);
  unsigned short* Plb   = (unsigned short*)(ws + OFF_PL);
  _Float16*       vuth  = (_Float16*)(ws + OFF_VUTH);
  _Float16*       vutl  = (_Float16*)(ws + OFF_VUTL);
  unsigned short* xh    = (unsigned short*)(ws + OFF_XH);
  unsigned short* xl    = (unsigned short*)(ws + OFF_XL);
  float*          Wb    = (float*)(ws + OFF_W);

  k_prep  <<<dim3(5632),   256, 0, stream>>>((const float*)d_in[1], (const float*)d_in[2],
                                             (const float*)d_in[3], (const float*)d_in[4],
                                             (const float*)d_in[5], (const float*)d_in[6],
                                             x, wth, wtl, xh, xl);
  k_proj  <<<dim3(384),    256, 0, stream>>>(xh, xl, wth, wtl, projh, projl, vct, vuth, vutl);
  k_p2    <<<dim3(152,4),  256, 0, stream>>>(projh, projl, vuth, vutl, sg, t1d, Wb);
  k_scan  <<<dim3(64,4),   256, 0, stream>>>(Wb, Phb, Plb);
  k_p3    <<<dim3(136,4),  256, 0, stream>>>(projh, projl, t1d, sg, Phb, Plb, lg);
  k_p4    <<<dim3(64,4),   256, 0, stream>>>(lg, vct, (float*)d_out);
}